// Round 1
// baseline (518.821 us; speedup 1.0000x reference)
//
#include <hip/hip_runtime.h>

#define AS1 __attribute__((address_space(1)))
#define AS3 __attribute__((address_space(3)))

using u16 = unsigned short;
using u32 = unsigned int;
typedef __attribute__((ext_vector_type(8))) short bf16x8;
typedef __attribute__((ext_vector_type(4))) float f32x4;

constexpr int Bn    = 32;
constexpr int Cn    = 64;
constexpr int Tn    = 16384;
constexpr int Kk    = 21;
constexpr int TCn   = 16364;   // Tn - (Kk-1)
constexpr int TPADn = 16416;   // Tn + 32 pad rows (zero) so tile-63 staging stays in-bounds

__device__ __forceinline__ u16 f2bf(float f) {
  union { float f; u32 u; } v; v.f = f;
  u32 u = v.u;
  u += 0x7fffu + ((u >> 16) & 1u);   // RNE
  return (u16)(u >> 16);
}
__device__ __forceinline__ float bf2f(u16 h) {
  union { u32 u; float f; } v; v.u = ((u32)h) << 16; return v.f;
}
// order-preserving float<->uint for atomicMax on signed floats
__device__ __forceinline__ u32 encf(float f) {
  union { float f; u32 u; } v; v.f = f;
  return (v.u & 0x80000000u) ? ~v.u : (v.u | 0x80000000u);
}
__device__ __forceinline__ float decf(u32 u) {
  union { u32 u; float f; } v;
  v.u = (u & 0x80000000u) ? (u ^ 0x80000000u) : ~u;
  return v.f;
}
__device__ __forceinline__ void gload_lds16(const void* g, void* l) {
  // per-lane 16B global -> (wave-uniform LDS base + lane*16)
  __builtin_amdgcn_global_load_lds((const AS1 u32*)g, (AS3 u32*)l, 16, 0, 0);
}

// ---------------------------------------------------------------------------
// Kernel 1: x (B,C,T) fp32 -> x_t[b][t][ci ^ ((t&7)*8)] bf16, zero pad rows.
// ---------------------------------------------------------------------------
__global__ __launch_bounds__(256) void transpose_x(const float* __restrict__ x,
                                                   u16* __restrict__ x_t) {
  __shared__ u16 lt[64][72];               // +8 u16 row pad (keeps 16B align: 144B rows)
  const int bx = blockIdx.x;
  const int b  = bx >> 8;
  const int tt = bx & 255;
  const int t0 = tt * 64;
  const int tid = threadIdx.x;
  const int ci   = tid >> 2;
  const int part = tid & 3;
  const float* xp = x + (size_t)(b * 64 + ci) * Tn + t0 + part * 16;
#pragma unroll
  for (int u = 0; u < 4; ++u) {
    float4 v = *(const float4*)(xp + u * 4);
    float vv[4] = {v.x, v.y, v.z, v.w};
#pragma unroll
    for (int e = 0; e < 4; ++e) {
      int tl = part * 16 + u * 4 + e;
      lt[tl][ci ^ ((tl & 7) * 8)] = f2bf(vv[e]);
    }
  }
  __syncthreads();
  const int row = tid >> 2;
  const int seg = tid & 3;
  u16* op = x_t + ((size_t)b * TPADn + t0 + row) * 64 + seg * 16;
  *(uint4*)op       = *(const uint4*)&lt[row][seg * 16];
  *(uint4*)(op + 8) = *(const uint4*)&lt[row][seg * 16 + 8];
  if (tt == 0) {  // zero the 32 pad rows once per b: 32*64 u16 = 4096B = 256 x 16B
    uint4 z = make_uint4(0u, 0u, 0u, 0u);
    uint4* pz = (uint4*)(x_t + ((size_t)b * TPADn + Tn) * 64);
    pz[tid] = z;
  }
}

// ---------------------------------------------------------------------------
// Kernel 2: repack weights into MFMA A-fragment order.
// chunk c in [0,42): tap k = c>>1, ci-half cb = (c&1)*32.
// wf[((c*4+ct)*64 + lane)*8 + j] = bf16( w[co=ct*16+(lane&15)][cb+(lane>>4)*8+j][k] )
// ---------------------------------------------------------------------------
__global__ __launch_bounds__(256) void repack_w(const float* __restrict__ w1,
                                                const float* __restrict__ w2,
                                                u16* __restrict__ wf1,
                                                u16* __restrict__ wf2) {
  const int bx = blockIdx.x;
  const int cv = bx / 42;
  const int c  = bx % 42;
  const float* w = cv ? w2 : w1;
  u16* wf = cv ? wf2 : wf1;
  const int tid  = threadIdx.x;
  const int ct   = tid >> 6;
  const int lane = tid & 63;
  const int q  = lane >> 4;
  const int rr = lane & 15;
  const int k  = c >> 1;
  const int cb = (c & 1) * 32;
  const int co = ct * 16 + rr;
  u16 us[8] __attribute__((aligned(16)));
#pragma unroll
  for (int j = 0; j < 8; ++j) {
    int ci = cb + q * 8 + j;
    us[j] = f2bf(w[((size_t)co * 64 + ci) * Kk + k]);
  }
  *(uint4*)&wf[((size_t)(c * 4 + ct) * 64 + lane) * 8] = *(const uint4*)us;
}

// ---------------------------------------------------------------------------
// Kernel 3: implicit-GEMM conv via mfma_f32_16x16x32_bf16, both convs.
// Block: one (cv, b, 256-wide t tile), 64 co. Wave: 4 co-tiles x 4 t-tiles.
// Also accumulates per-channel sum/sumsq (masked to t<TC) for BN.
// ---------------------------------------------------------------------------
__global__ __launch_bounds__(256, 2) void conv_mfma(const u16* __restrict__ x_t,
                                                    const u16* __restrict__ wf1,
                                                    const u16* __restrict__ wf2,
                                                    u16* __restrict__ y1,
                                                    u16* __restrict__ y2,
                                                    float* __restrict__ stats) {
  __shared__ u16 xs[280 * 64];         // 35840 B: x rows t0..t0+279 (flat copy of x_t)
  __shared__ u16 wsw[7 * 4 * 64 * 8];  // 28672 B: 7 chunks of A-fragments
  __shared__ float sred[128];          // per-channel {sum, sumsq}

  const int bid  = blockIdx.x;
  const int cv   = bid & 1;
  const int tmp  = bid >> 1;
  const int tile = tmp & 63;
  const int b    = tmp >> 6;
  const int t0   = tile * 256;
  const int tid  = threadIdx.x;
  const int w    = tid >> 6;    // wave id
  const int lane = tid & 63;
  const int q    = lane >> 4;
  const int r    = lane & 15;
  const u16* wf  = cv ? wf2 : wf1;

  if (tid < 128) sred[tid] = 0.f;

  // stage x tile: 280 rows * 128B = 35 x 1KB chunks
  const u16* xg = x_t + ((size_t)b * TPADn + t0) * 64;
  for (int s = w; s < 35; s += 4)
    gload_lds16(xg + (size_t)s * 512 + lane * 8, &xs[s * 512]);

  f32x4 acc[4][4];
#pragma unroll
  for (int a = 0; a < 4; ++a)
#pragma unroll
    for (int t = 0; t < 4; ++t)
      acc[a][t] = (f32x4){0.f, 0.f, 0.f, 0.f};

  for (int g = 0; g < 6; ++g) {
    // stage weight group g (7 chunks = 28KB = 28 x 1KB)
    const u16* wg = wf + (size_t)g * 14336;
    for (int s = w; s < 28; s += 4)
      gload_lds16(wg + (size_t)s * 512 + lane * 8, &wsw[s * 512]);
    __syncthreads();   // staging (and, for g=0, x tile) visible
#pragma unroll
    for (int cl = 0; cl < 7; ++cl) {
      const int c  = g * 7 + cl;
      const int k  = c >> 1;
      const int cb = (c & 1) * 32;
      bf16x8 af[4];
#pragma unroll
      for (int ct = 0; ct < 4; ++ct)
        af[ct] = *(const bf16x8*)&wsw[((cl * 4 + ct) * 64 + lane) * 8];
      bf16x8 bx[4];
#pragma unroll
      for (int tt = 0; tt < 4; ++tt) {
        int p = w * 64 + tt * 16 + r + k;
        int cidx = (cb + q * 8) ^ ((p & 7) * 8);   // bake the x_t XOR swizzle
        bx[tt] = *(const bf16x8*)&xs[p * 64 + cidx];
      }
#pragma unroll
      for (int ct = 0; ct < 4; ++ct)
#pragma unroll
        for (int tt = 0; tt < 4; ++tt)
          acc[ct][tt] = __builtin_amdgcn_mfma_f32_16x16x32_bf16(af[ct], bx[tt], acc[ct][tt], 0, 0, 0);
    }
    __syncthreads();   // group's reads done before next staging / epilogue LDS reuse
  }

  // ---- BN statistics (mask t >= TC) ----
#pragma unroll
  for (int ct = 0; ct < 4; ++ct)
#pragma unroll
    for (int i = 0; i < 4; ++i) {
      float sv = 0.f, sq = 0.f;
#pragma unroll
      for (int tt = 0; tt < 4; ++tt) {
        int tg = t0 + w * 64 + tt * 16 + r;
        if (tg < TCn) {
          float v = acc[ct][tt][i];
          sv += v; sq += v * v;
        }
      }
#pragma unroll
      for (int m = 1; m < 16; m <<= 1) {
        sv += __shfl_xor(sv, m, 64);
        sq += __shfl_xor(sq, m, 64);
      }
      if (r == 0) {
        int co = ct * 16 + q * 4 + i;
        atomicAdd(&sred[co * 2], sv);
        atomicAdd(&sred[co * 2 + 1], sq);
      }
    }

  // ---- store y_t[b][t][co] bf16 via LDS transpose (reuse xs) ----
  u16* ys = xs;   // 256*64 u16 = 32KB <= 35840B
#pragma unroll
  for (int ct = 0; ct < 4; ++ct)
#pragma unroll
    for (int tt = 0; tt < 4; ++tt) {
      int tl = w * 64 + tt * 16 + r;
#pragma unroll
      for (int i = 0; i < 4; ++i) {
        int co = ct * 16 + q * 4 + i;
        ys[tl * 64 + co] = f2bf(acc[ct][tt][i]);
      }
    }
  __syncthreads();
  u16* yo = (cv ? y2 : y1) + ((size_t)b * Tn + t0) * 64;
#pragma unroll
  for (int m = 0; m < 8; ++m) {
    int idx = (m * 256 + tid) * 8;
    *(uint4*)(yo + idx) = *(const uint4*)(ys + idx);
  }
  if (tid < 128) atomicAdd(&stats[cv * 128 + tid], sred[tid]);
}

// ---------------------------------------------------------------------------
// Kernel 4: finalize BN affine per channel: a = g*rsqrt(var+eps), b = beta - mean*a
// ---------------------------------------------------------------------------
__global__ void bn_finalize(const float* __restrict__ stats,
                            const float* __restrict__ g1, const float* __restrict__ b1,
                            const float* __restrict__ g2, const float* __restrict__ b2,
                            float* __restrict__ ab) {
  int tid = threadIdx.x;
  if (tid >= 128) return;
  int cv = tid >> 6;
  int co = tid & 63;
  float s  = stats[cv * 128 + co * 2];
  float sq = stats[cv * 128 + co * 2 + 1];
  const float N = 32.0f * 16364.0f;
  float mean = s / N;
  float var  = sq / N - mean * mean;
  if (var < 0.f) var = 0.f;
  float a  = (cv ? g2 : g1)[co] * rsqrtf(var + 1e-5f);
  float bb = (cv ? b2 : b1)[co] - mean * a;
  ab[cv * 128 + co * 2]     = a;
  ab[cv * 128 + co * 2 + 1] = bb;
}

// ---------------------------------------------------------------------------
// Kernel 5: SPP. Block = (b, 1/16th of t). Lane = channel (coalesced y_t reads).
// Ranges: bin0=[0,kern2), bin1=[str2,L), level0=[0,L). Max (y1) + sums (y2).
// ---------------------------------------------------------------------------
__global__ __launch_bounds__(256) void spp(const u16* __restrict__ y1,
                                           const u16* __restrict__ y2,
                                           const float* __restrict__ ab,
                                           const int* __restrict__ orig_len,
                                           u32* __restrict__ featU) {
  const int bx = blockIdx.x;
  const int b  = bx >> 4;
  const int ch = bx & 15;
  const int tid = threadIdx.x;
  const int co  = tid & 63;
  const int sub = tid >> 6;
  const int L     = orig_len[b] - 20;
  const int str2  = L >> 1;        // floor(L/2)
  const int kern2 = L - str2;      // ceil(L/2)
  const float a1 = ab[co * 2],       c1 = ab[co * 2 + 1];
  const float a2 = ab[128 + co * 2], c2 = ab[128 + co * 2 + 1];
  float m1 = -3.4e38f, m2 = -3.4e38f;
  float s0 = 0.f, sb0 = 0.f, sb1 = 0.f;
  const int tbase = ch * 1024;
  int tend = tbase + 1024;
  if (tend > L) tend = L;
  const u16* p1 = y1 + (size_t)b * Tn * 64 + co;
  const u16* p2 = y2 + (size_t)b * Tn * 64 + co;
  for (int t = tbase + sub; t < tend; t += 4) {
    float v1 = bf2f(p1[(size_t)t * 64]);
    float v2 = bf2f(p2[(size_t)t * 64]);
    float z1 = fmaf(a1, v1, c1); z1 = z1 > 0.f ? z1 : 0.01f * z1;
    float z2 = fmaf(a2, v2, c2); z2 = z2 > 0.f ? z2 : 0.01f * z2;
    if (t < kern2)  { m1 = fmaxf(m1, z1); sb0 += z2; }
    if (t >= str2)  { m2 = fmaxf(m2, z1); sb1 += z2; }  // t<L via tend
    s0 += z2;
  }
  u32* fb = featU + (size_t)b * 384;
  float* ff = (float*)fb;
  u32 e1 = encf(m1), e2 = encf(m2);
  atomicMax(&fb[co], e1);                 // level0 max = max(bin0,bin1)
  atomicMax(&fb[co], e2);
  atomicMax(&fb[64 + co * 2], e1);
  atomicMax(&fb[64 + co * 2 + 1], e2);
  atomicAdd(&ff[192 + co], s0);
  atomicAdd(&ff[256 + co * 2], sb0);
  atomicAdd(&ff[256 + co * 2 + 1], sb1);
}

// ---------------------------------------------------------------------------
// Kernel 6: FC. feat(32,384) @ fc_w^T(384,2) + fc_b. Decode maxes, scale avgs.
// ---------------------------------------------------------------------------
__global__ void fc(const u32* __restrict__ featU,
                   const int* __restrict__ orig_len,
                   const float* __restrict__ fc_w,
                   const float* __restrict__ fc_b,
                   float* __restrict__ out) {
  const int tid  = threadIdx.x;        // 256
  const int pair = tid >> 2;           // (b,n)
  const int part = tid & 3;
  const int b = pair >> 1;
  const int n = pair & 1;
  const int L = orig_len[b] - 20;
  const int kern2 = L - (L >> 1);
  const u32* fb = featU + (size_t)b * 384;
  const float* ff = (const float*)fb;
  float acc = 0.f;
  for (int j = part; j < 384; j += 4) {
    float fv;
    if (j < 192)      fv = decf(fb[j]);
    else if (j < 256) fv = ff[j] / (float)L;
    else              fv = ff[j] / (float)kern2;
    acc += fv * fc_w[n * 384 + j];
  }
  acc += __shfl_xor(acc, 1, 64);
  acc += __shfl_xor(acc, 2, 64);
  if (part == 0) out[b * 2 + n] = acc + fc_b[n];
}

// ---------------------------------------------------------------------------
extern "C" void kernel_launch(void* const* d_in, const int* in_sizes, int n_in,
                              void* d_out, int out_size, void* d_ws, size_t ws_size,
                              hipStream_t stream) {
  const float* x        = (const float*)d_in[0];
  const int*   orig_len = (const int*)d_in[1];
  const float* w1  = (const float*)d_in[2];
  const float* g1  = (const float*)d_in[3];
  const float* b1  = (const float*)d_in[4];
  const float* w2  = (const float*)d_in[5];
  const float* g2  = (const float*)d_in[6];
  const float* b2  = (const float*)d_in[7];
  const float* fcw = (const float*)d_in[8];
  const float* fcb = (const float*)d_in[9];
  float* out = (float*)d_out;

  char* ws = (char*)d_ws;
  const size_t XT_BYTES = (size_t)Bn * TPADn * 64 * 2;   // 67,239,936
  const size_t Y_BYTES  = (size_t)Bn * Tn * 64 * 2;      // 67,108,864
  const size_t WF_BYTES = (size_t)42 * 4 * 64 * 8 * 2;   // 172,032
  size_t off = 0;
  u16* x_t = (u16*)(ws + off); off += XT_BYTES;
  u16* y1  = (u16*)(ws + off); off += Y_BYTES;
  u16* y2  = (u16*)(ws + off); off += Y_BYTES;
  u16* wf1 = (u16*)(ws + off); off += WF_BYTES;
  u16* wf2 = (u16*)(ws + off); off += WF_BYTES;
  float* stats = (float*)(ws + off);                 // 2*64*2 floats = 1024B
  float* abuf  = (float*)(ws + off + 1024);          // 1024B
  u32*   featU = (u32*)(ws + off + 2048);            // 32*384*4 = 49152B
  const size_t SMALL_BYTES = 1024 + 1024 + 49152;

  hipMemsetAsync(ws + off, 0, SMALL_BYTES, stream);
  transpose_x<<<Bn * 256, 256, 0, stream>>>(x, x_t);
  repack_w<<<84, 256, 0, stream>>>(w1, w2, wf1, wf2);
  conv_mfma<<<Bn * 64 * 2, 256, 0, stream>>>(x_t, wf1, wf2, y1, y2, stats);
  bn_finalize<<<1, 128, 0, stream>>>(stats, g1, b1, g2, b2, abuf);
  spp<<<Bn * 16, 256, 0, stream>>>(y1, y2, abuf, orig_len, featU);
  fc<<<1, 256, 0, stream>>>(featU, orig_len, fcw, fcb, out);
  (void)in_sizes; (void)n_in; (void)out_size; (void)ws_size;
}